// Round 13
// baseline (175.694 us; speedup 1.0000x reference)
//
#include <hip/hip_runtime.h>
#include <hip/hip_bf16.h>

// AdjustedNonLocalBlock: 3x conv1x1 -> attention(S=4096,D=64,B=4) -> conv1x1 + residual.
// fp32 I/O; bf16 internals for MFMA. 2 kernels:
//   1. qkv:  n-tile 32, grid 512: x->LDS->MFMA convs -> Q[n][64], K[n][64], Vt[64][n]
//   2. attn: ksplit 16, grid 1024: S^T=K*Q^T; P=2^S (native v_exp_f32) ->LDS; O+=P*V;
//            split-K ticket: LAST block per (b,qt) combines 16 partials, MFMA-projects
//            through W and writes out (+Wb +x0). No spin -> no co-residency needed.

typedef unsigned int   u32;
typedef unsigned short u16;
typedef __attribute__((ext_vector_type(8))) short short8;   // 8x bf16 (MFMA A/B frag)
typedef __attribute__((ext_vector_type(4))) short short4v;  // 4x bf16 (LDS P store)
typedef __attribute__((ext_vector_type(4))) float f32x4;    // MFMA C/D frag

#define LOG2E 1.4426950408889634f
#define KSPLIT 16

__device__ __forceinline__ float b2f(u16 v) {
  union { u32 u; float f; } x; x.u = ((u32)v) << 16; return x.f;
}
__device__ __forceinline__ u16 f2b(float f) {
  u32 u = __float_as_uint(f);
  return (u16)((u + 0x8000u) >> 16);
}
__device__ __forceinline__ short8 load_w_frag(const float* p, float s) {
  const float4 f0 = ((const float4*)p)[0];
  const float4 f1 = ((const float4*)p)[1];
  union { u32 w[4]; short8 s8; } r;
  r.w[0] = (u32)f2b(f0.x * s) | ((u32)f2b(f0.y * s) << 16);
  r.w[1] = (u32)f2b(f0.z * s) | ((u32)f2b(f0.w * s) << 16);
  r.w[2] = (u32)f2b(f1.x * s) | ((u32)f2b(f1.y * s) << 16);
  r.w[3] = (u32)f2b(f1.z * s) | ((u32)f2b(f1.w * s) << 16);
  return r.s8;
}

// ---------------- workspace layout (bytes) ----------------
// Q    [4][4096][64]  bf16 @ 0     (2 MB)
// K    [4][4096][64]  bf16 @ 2 MB  (2 MB)
// Vt   [4][64][4096]  bf16 @ 4 MB  (2 MB)
// Opart[16][4][4096][64] bf16 @ 6 MB (32 MB)
// Lp   [16][4][4096] f32 @ 38 MB   (1 MB)
// cnt  [64] u32 @ 39 MB (split-K tickets; memset to 0 each launch)

// grid (128 n-tiles of 32, 4 batches), block 256 = 4 waves — unchanged from R12.
__global__ __launch_bounds__(256) void qkv_kernel(
    const float* __restrict__ x0, const float* __restrict__ x1,
    const float* __restrict__ tw, const float* __restrict__ tb,
    const float* __restrict__ pw, const float* __restrict__ pb,
    const float* __restrict__ gw, const float* __restrict__ gb,
    u16* __restrict__ Q, u16* __restrict__ K, u16* __restrict__ Vt)
{
  const int n0 = blockIdx.x * 32;
  const int b  = blockIdx.y;
  const int t  = threadIdx.x;

  __shared__ __align__(16) short xt[2][32][136];   // [tensor][n][c], +8 pad

  #pragma unroll 8
  for (int i = 0; i < 32; ++i) {
    const int idx = i * 256 + t;
    const int tensor = idx >> 12;
    const int c = (idx >> 5) & 127;
    const int n = idx & 31;
    const float v = (tensor ? x1 : x0)[((size_t)b * 128 + c) * 4096 + n0 + n];
    xt[tensor][n][c] = (short)f2b(v);
  }
  asm volatile("" ::: "memory");
  __syncthreads();

  const int wave = t >> 6;
  const int lane = t & 63;
  const int quad = lane >> 4, l15 = lane & 15;

  if (wave < 2) {
    const int conv = wave;              // 0=theta(x1)->Q, 1=phi(x0)->K
    const float* wsrc = conv ? pw : tw;
    const float  ws   = conv ? 1.f : LOG2E;
    const short* xl   = &xt[conv ? 0 : 1][0][0];

    f32x4 acc[2][4];
    #pragma unroll
    for (int i = 0; i < 2; ++i)
      #pragma unroll
      for (int j = 0; j < 4; ++j) acc[i][j] = (f32x4){0.f, 0.f, 0.f, 0.f};

    #pragma unroll
    for (int kk = 0; kk < 4; ++kk) {
      short8 wf[4], xf[2];
      #pragma unroll
      for (int ot = 0; ot < 4; ++ot)
        wf[ot] = load_w_frag(wsrc + (ot * 16 + l15) * 128 + kk * 32 + quad * 8, ws);
      #pragma unroll
      for (int nt = 0; nt < 2; ++nt)
        xf[nt] = *(const short8*)(xl + (nt * 16 + l15) * 136 + kk * 32 + quad * 8);
      #pragma unroll
      for (int i = 0; i < 2; ++i)
        #pragma unroll
        for (int j = 0; j < 4; ++j)
          acc[i][j] = __builtin_amdgcn_mfma_f32_16x16x32_bf16(xf[i], wf[j], acc[i][j], 0, 0, 0);
    }

    u16* dst = (conv ? K : Q) + (size_t)b * 4096 * 64;
    const float* bias = conv ? pb : tb;
    const float bscale = conv ? 1.f : LOG2E;
    #pragma unroll
    for (int ot = 0; ot < 4; ++ot) {
      const float bv = bias[ot * 16 + l15] * bscale;
      #pragma unroll
      for (int nt = 0; nt < 2; ++nt)
        #pragma unroll
        for (int r = 0; r < 4; ++r) {
          const int n = n0 + nt * 16 + quad * 4 + r;
          dst[(size_t)n * 64 + ot * 16 + l15] = f2b(acc[nt][ot][r] + bv);
        }
    }
  } else {
    const int oh = wave - 2;
    const short* xl = &xt[0][0][0];

    f32x4 acc[2][2];
    #pragma unroll
    for (int i = 0; i < 2; ++i)
      #pragma unroll
      for (int j = 0; j < 2; ++j) acc[i][j] = (f32x4){0.f, 0.f, 0.f, 0.f};

    #pragma unroll
    for (int kk = 0; kk < 4; ++kk) {
      short8 wf[2], xf[2];
      #pragma unroll
      for (int ot = 0; ot < 2; ++ot)
        wf[ot] = load_w_frag(gw + ((oh * 2 + ot) * 16 + l15) * 128 + kk * 32 + quad * 8, 1.f);
      #pragma unroll
      for (int nt = 0; nt < 2; ++nt)
        xf[nt] = *(const short8*)(xl + (nt * 16 + l15) * 136 + kk * 32 + quad * 8);
      #pragma unroll
      for (int i = 0; i < 2; ++i)
        #pragma unroll
        for (int j = 0; j < 2; ++j)
          acc[i][j] = __builtin_amdgcn_mfma_f32_16x16x32_bf16(wf[i], xf[j], acc[i][j], 0, 0, 0);
    }

    u16* dst = Vt + (size_t)b * 64 * 4096;
    #pragma unroll
    for (int ot = 0; ot < 2; ++ot)
      #pragma unroll
      for (int r = 0; r < 4; ++r) {
        const int o = (oh * 2 + ot) * 16 + quad * 4 + r;
        const float bv = gb[o];
        #pragma unroll
        for (int nc = 0; nc < 2; ++nc)
          dst[(size_t)o * 4096 + n0 + nc * 16 + l15] = f2b(acc[ot][nc][r] + bv);
      }
  }
}

// grid (16 qt, 4 b, 16 ks) = 1024 blocks. Verified attention core + split-K winner epilogue.
__global__ __launch_bounds__(256) void attn_kernel(
    const u16* __restrict__ Q, const u16* __restrict__ K,
    const u16* __restrict__ Vt, u16* __restrict__ Opart,
    float* __restrict__ Lp, u32* __restrict__ cnt,
    const float* __restrict__ Wf, const float* __restrict__ Wbf,
    const float* __restrict__ x0, float* __restrict__ out)
{
  const int qt = blockIdx.x, b = blockIdx.y, ks = blockIdx.z;
  const int t    = threadIdx.x;
  const int wave = t >> 6;
  const int lane = t & 63;
  const int quad = lane >> 4;
  const int l15  = lane & 15;

  __shared__ __align__(16) short P_lds[4][64][72];   // 36864 B; reused as Y[256][72] by winner
  __shared__ float rinvs[256];
  __shared__ u32 tick;
  short* pl = &P_lds[wave][0][0];

  const int q0 = qt * 256 + wave * 64;
  const u16* Qb = Q  + (size_t)b * 4096 * 64;
  const u16* Kb = K  + (size_t)b * 4096 * 64;
  const u16* Vb = Vt + (size_t)b * 64 * 4096;

  short8 qf[4][2];
  #pragma unroll
  for (int nt = 0; nt < 4; ++nt) {
    const u16* qp = Qb + (size_t)(q0 + nt * 16 + l15) * 64 + quad * 8;
    qf[nt][0] = *(const short8*)qp;
    qf[nt][1] = *(const short8*)(qp + 32);
  }

  f32x4 oacc[4][4];
  #pragma unroll
  for (int i = 0; i < 4; ++i)
    #pragma unroll
    for (int j = 0; j < 4; ++j)
      oacc[i][j] = (f32x4){0.f, 0.f, 0.f, 0.f};
  float lsum[4] = {0.f, 0.f, 0.f, 0.f};

  const int kbase = ks * (4096 / KSPLIT);
  const int NKT   = 4096 / KSPLIT / 64;   // 4

  short8 kf[4][2];
  #pragma unroll
  for (int mt = 0; mt < 4; ++mt) {
    const u16* kp = Kb + (size_t)(kbase + mt * 16 + l15) * 64 + quad * 8;
    kf[mt][0] = *(const short8*)kp;
    kf[mt][1] = *(const short8*)(kp + 32);
  }

  for (int kt = 0; kt < NKT; ++kt) {
    const int k0 = kbase + kt * 64;

    short8 vf[4][2];
    #pragma unroll
    for (int nd = 0; nd < 4; ++nd) {
      const u16* vp = Vb + (size_t)(nd * 16 + l15) * 4096 + k0 + quad * 8;
      vf[nd][0] = *(const short8*)vp;
      vf[nd][1] = *(const short8*)(vp + 32);
    }

    #pragma unroll
    for (int mt = 0; mt < 4; ++mt) {
      #pragma unroll
      for (int nt = 0; nt < 4; ++nt) {
        f32x4 s = {0.f, 0.f, 0.f, 0.f};
        s = __builtin_amdgcn_mfma_f32_16x16x32_bf16(kf[mt][0], qf[nt][0], s, 0, 0, 0);
        s = __builtin_amdgcn_mfma_f32_16x16x32_bf16(kf[mt][1], qf[nt][1], s, 0, 0, 0);
        // native v_exp_f32 (logits bounded -> fast path safe; libm exp2f expands)
        float p0 = __builtin_amdgcn_exp2f(s[0]);
        float p1 = __builtin_amdgcn_exp2f(s[1]);
        float p2 = __builtin_amdgcn_exp2f(s[2]);
        float p3 = __builtin_amdgcn_exp2f(s[3]);
        lsum[nt] += (p0 + p1) + (p2 + p3);
        u32 u0 = __float_as_uint(p0) + 0x8000u;
        u32 u1 = __float_as_uint(p1) + 0x8000u;
        u32 u2 = __float_as_uint(p2) + 0x8000u;
        u32 u3 = __float_as_uint(p3) + 0x8000u;
        union { uint2 u; short4v s4; } pk;
        pk.u.x = __builtin_amdgcn_perm(u1, u0, 0x07060302u);
        pk.u.y = __builtin_amdgcn_perm(u3, u2, 0x07060302u);
        *(short4v*)(pl + (nt * 16 + l15) * 72 + mt * 16 + quad * 4) = pk.s4;
      }
    }

    if (kt < NKT - 1) {
      #pragma unroll
      for (int mt = 0; mt < 4; ++mt) {
        const u16* kp = Kb + (size_t)(k0 + 64 + mt * 16 + l15) * 64 + quad * 8;
        kf[mt][0] = *(const short8*)kp;
        kf[mt][1] = *(const short8*)(kp + 32);
      }
    }

    asm volatile("" ::: "memory");

    #pragma unroll
    for (int mq = 0; mq < 4; ++mq) {
      const short* pr = pl + (mq * 16 + l15) * 72 + quad * 8;
      short8 pa0 = *(const short8*)pr;
      short8 pa1 = *(const short8*)(pr + 32);
      #pragma unroll
      for (int nd = 0; nd < 4; ++nd) {
        oacc[mq][nd] = __builtin_amdgcn_mfma_f32_16x16x32_bf16(pa0, vf[nd][0], oacc[mq][nd], 0, 0, 0);
        oacc[mq][nd] = __builtin_amdgcn_mfma_f32_16x16x32_bf16(pa1, vf[nd][1], oacc[mq][nd], 0, 0, 0);
      }
    }

    asm volatile("" ::: "memory");
  }

  #pragma unroll
  for (int nt = 0; nt < 4; ++nt) {
    float v = lsum[nt];
    v += __shfl_xor(v, 16, 64);
    v += __shfl_xor(v, 32, 64);
    lsum[nt] = v;
  }
  float* LpB = Lp + ((size_t)ks * 4 + b) * 4096;
  if (quad == 0) {
    #pragma unroll
    for (int nt = 0; nt < 4; ++nt)
      LpB[q0 + nt * 16 + l15] = lsum[nt];
  }

  u16* Ob = Opart + ((size_t)ks * 4 + b) * 4096 * 64;
  #pragma unroll
  for (int mq = 0; mq < 4; ++mq)
    #pragma unroll
    for (int nd = 0; nd < 4; ++nd)
      #pragma unroll
      for (int r = 0; r < 4; ++r) {
        const int q = q0 + mq * 16 + quad * 4 + r;
        Ob[(size_t)q * 64 + nd * 16 + l15] = f2b(oacc[mq][nd][r]);
      }

  // ---- split-K ticket: last block per (b,qt) combines + projects ----
  __syncthreads();   // all waves' global stores drained (barrier implies vmcnt(0))
  if (t == 0) {
    __builtin_amdgcn_fence(__ATOMIC_RELEASE, "agent");
    tick = __hip_atomic_fetch_add(&cnt[b * 16 + qt], 1u,
                                  __ATOMIC_RELAXED, __HIP_MEMORY_SCOPE_AGENT);
  }
  __syncthreads();
  if (tick != KSPLIT - 1) return;
  __builtin_amdgcn_fence(__ATOMIC_ACQUIRE, "agent");

  // winner: Y[256 q][64 ci] = sum_ks(Opart)/sum_ks(Lp) into LDS (exact arena reuse)
  auto Yl = (short (*)[72]) & P_lds[0][0][0];

  {  // rinvs[t] for q = qt*256 + t
    float l = 0.f;
    #pragma unroll
    for (int k2 = 0; k2 < KSPLIT; ++k2)
      l += Lp[((size_t)k2 * 4 + b) * 4096 + qt * 256 + t];
    rinvs[t] = 1.f / l;
  }
  asm volatile("" ::: "memory");
  __syncthreads();

  #pragma unroll
  for (int pass = 0; pass < 8; ++pass) {
    const int ql = pass * 32 + (t >> 3);   // local q row 0..255
    const int j  = t & 7;                  // 8-ch chunk (one uint4)
    const int qg = qt * 256 + ql;

    float a[8];
    #pragma unroll
    for (int k = 0; k < 8; ++k) a[k] = 0.f;
    #pragma unroll
    for (int k2 = 0; k2 < KSPLIT; ++k2) {
      const uint4 r = *(const uint4*)(Opart + (((size_t)k2 * 4 + b) * 4096 + qg) * 64 + j * 8);
      u32 wds[4] = {r.x, r.y, r.z, r.w};
      #pragma unroll
      for (int k = 0; k < 4; ++k) {
        a[2 * k]     += __uint_as_float(wds[k] << 16);
        a[2 * k + 1] += __uint_as_float(wds[k] & 0xffff0000u);
      }
    }
    const float rinv = rinvs[ql];
    union { u32 w[4]; short8 s8; } pk;
    #pragma unroll
    for (int k = 0; k < 4; ++k)
      pk.w[k] = (u32)f2b(a[2 * k] * rinv) | ((u32)f2b(a[2 * k + 1] * rinv) << 16);
    *(short8*)&Yl[ql][j * 8] = pk.s8;
  }
  asm volatile("" ::: "memory");
  __syncthreads();

  // proj: wave w -> o in [w*32, w*32+32); C[o][n] = mfma(W-frag, Y-frag); + Wb + x0
  short8 wfr[2][2];   // [kk][ot]
  #pragma unroll
  for (int kk = 0; kk < 2; ++kk)
    #pragma unroll
    for (int ot = 0; ot < 2; ++ot)
      wfr[kk][ot] = load_w_frag(Wf + ((wave * 2 + ot) * 16 + l15) * 64 + kk * 32 + quad * 8, 1.f);
  float bv[2][4];
  #pragma unroll
  for (int ot = 0; ot < 2; ++ot)
    #pragma unroll
    for (int r = 0; r < 4; ++r)
      bv[ot][r] = Wbf[(wave * 2 + ot) * 16 + quad * 4 + r];

  #pragma unroll
  for (int nt = 0; nt < 16; ++nt) {
    short8 yf0 = *(const short8*)&Yl[nt * 16 + l15][quad * 8];
    short8 yf1 = *(const short8*)&Yl[nt * 16 + l15][32 + quad * 8];
    f32x4 acc[2];
    #pragma unroll
    for (int ot = 0; ot < 2; ++ot) {
      acc[ot] = (f32x4){0.f, 0.f, 0.f, 0.f};
      acc[ot] = __builtin_amdgcn_mfma_f32_16x16x32_bf16(wfr[0][ot], yf0, acc[ot], 0, 0, 0);
      acc[ot] = __builtin_amdgcn_mfma_f32_16x16x32_bf16(wfr[1][ot], yf1, acc[ot], 0, 0, 0);
    }
    #pragma unroll
    for (int ot = 0; ot < 2; ++ot)
      #pragma unroll
      for (int r = 0; r < 4; ++r) {
        const int o = (wave * 2 + ot) * 16 + quad * 4 + r;
        const size_t idx = ((size_t)(b * 128 + o)) * 4096 + qt * 256 + nt * 16 + l15;
        out[idx] = acc[ot][r] + bv[ot][r] + x0[idx];
      }
  }
}

extern "C" void kernel_launch(void* const* d_in, const int* in_sizes, int n_in,
                              void* d_out, int out_size, void* d_ws, size_t ws_size,
                              hipStream_t stream) {
  const float* x0 = (const float*)d_in[0];
  const float* x1 = (const float*)d_in[1];
  const float* gw = (const float*)d_in[2];
  const float* gb = (const float*)d_in[3];
  const float* tw = (const float*)d_in[4];
  const float* tb = (const float*)d_in[5];
  const float* pw = (const float*)d_in[6];
  const float* pb = (const float*)d_in[7];
  const float* Ww = (const float*)d_in[8];
  const float* Wb = (const float*)d_in[9];
  float* out = (float*)d_out;

  char* ws = (char*)d_ws;
  u16*   Qw    = (u16*)(ws + 0);
  u16*   Kw    = (u16*)(ws + (2u << 20));
  u16*   Vtw   = (u16*)(ws + (4u << 20));
  u16*   Opart = (u16*)(ws + (6u << 20));
  float* Lp    = (float*)(ws + (38u << 20));
  u32*   cnt   = (u32*)(ws + (39u << 20));   // 64 tickets

  hipMemsetAsync(cnt, 0, 64 * sizeof(u32), stream);   // ws is poisoned each call

  qkv_kernel<<<dim3(128, 4), dim3(256), 0, stream>>>(
      x0, x1, tw, tb, pw, pb, gw, gb, Qw, Kw, Vtw);

  attn_kernel<<<dim3(16, 4, KSPLIT), dim3(256), 0, stream>>>(
      Qw, Kw, Vtw, Opart, Lp, cnt, Ww, Wb, x0, out);
}

// Round 14
// 144.817 us; speedup vs baseline: 1.2132x; 1.2132x over previous
//
#include <hip/hip_runtime.h>
#include <hip/hip_bf16.h>

// AdjustedNonLocalBlock: 3x conv1x1 -> attention(S=4096,D=64,B=4) -> conv1x1 + residual.
// fp32 I/O; bf16 internals for MFMA. 3 kernels (R12 structure — the R13 split-K winner
// epilogue serialized on 64 blocks and doubled attn; reverted):
//   1. qkv:  n-tile 32, grid 512: x->LDS->MFMA convs -> Q[n][64], K[n][64], Vt[64][n]
//   2. attn: ksplit 16, grid 1024 (4 blocks/CU): S^T=K*Q^T; P=2^S via native v_exp_f32
//            (logits bounded, libm exp2f expansion was ~half of VALUBusy); O+=P*V
//   3. out:  n-tile 32, grid 512: Ysum/L -> LDS; MFMA proj; + Wb + x0 residual

typedef unsigned int   u32;
typedef unsigned short u16;
typedef __attribute__((ext_vector_type(8))) short short8;   // 8x bf16 (MFMA A/B frag)
typedef __attribute__((ext_vector_type(4))) short short4v;  // 4x bf16 (LDS P store)
typedef __attribute__((ext_vector_type(4))) float f32x4;    // MFMA C/D frag

#define LOG2E 1.4426950408889634f
#define KSPLIT 16

__device__ __forceinline__ float b2f(u16 v) {
  union { u32 u; float f; } x; x.u = ((u32)v) << 16; return x.f;
}
__device__ __forceinline__ u16 f2b(float f) {
  u32 u = __float_as_uint(f);
  return (u16)((u + 0x8000u) >> 16);
}
__device__ __forceinline__ short8 load_w_frag(const float* p, float s) {
  const float4 f0 = ((const float4*)p)[0];
  const float4 f1 = ((const float4*)p)[1];
  union { u32 w[4]; short8 s8; } r;
  r.w[0] = (u32)f2b(f0.x * s) | ((u32)f2b(f0.y * s) << 16);
  r.w[1] = (u32)f2b(f0.z * s) | ((u32)f2b(f0.w * s) << 16);
  r.w[2] = (u32)f2b(f1.x * s) | ((u32)f2b(f1.y * s) << 16);
  r.w[3] = (u32)f2b(f1.z * s) | ((u32)f2b(f1.w * s) << 16);
  return r.s8;
}

// ---------------- workspace layout (bytes) ----------------
// Q    [4][4096][64]  bf16 @ 0     (2 MB)
// K    [4][4096][64]  bf16 @ 2 MB  (2 MB)
// Vt   [4][64][4096]  bf16 @ 4 MB  (2 MB)
// Opart[16][4][4096][64] bf16 @ 6 MB (32 MB)
// Lp   [16][4][4096] f32 @ 38 MB   (1 MB)   -> 39 MB

// grid (128 n-tiles of 32, 4 batches), block 256 = 4 waves. LDS 17.4 KB.
__global__ __launch_bounds__(256) void qkv_kernel(
    const float* __restrict__ x0, const float* __restrict__ x1,
    const float* __restrict__ tw, const float* __restrict__ tb,
    const float* __restrict__ pw, const float* __restrict__ pb,
    const float* __restrict__ gw, const float* __restrict__ gb,
    u16* __restrict__ Q, u16* __restrict__ K, u16* __restrict__ Vt)
{
  const int n0 = blockIdx.x * 32;
  const int b  = blockIdx.y;
  const int t  = threadIdx.x;

  __shared__ __align__(16) short xt[2][32][136];   // [tensor][n][c], +8 pad

  #pragma unroll 8
  for (int i = 0; i < 32; ++i) {
    const int idx = i * 256 + t;
    const int tensor = idx >> 12;
    const int c = (idx >> 5) & 127;
    const int n = idx & 31;
    const float v = (tensor ? x1 : x0)[((size_t)b * 128 + c) * 4096 + n0 + n];
    xt[tensor][n][c] = (short)f2b(v);
  }
  asm volatile("" ::: "memory");
  __syncthreads();

  const int wave = t >> 6;
  const int lane = t & 63;
  const int quad = lane >> 4, l15 = lane & 15;

  if (wave < 2) {
    const int conv = wave;              // 0=theta(x1)->Q, 1=phi(x0)->K
    const float* wsrc = conv ? pw : tw;
    const float  ws   = conv ? 1.f : LOG2E;
    const short* xl   = &xt[conv ? 0 : 1][0][0];

    f32x4 acc[2][4];
    #pragma unroll
    for (int i = 0; i < 2; ++i)
      #pragma unroll
      for (int j = 0; j < 4; ++j) acc[i][j] = (f32x4){0.f, 0.f, 0.f, 0.f};

    #pragma unroll
    for (int kk = 0; kk < 4; ++kk) {
      short8 wf[4], xf[2];
      #pragma unroll
      for (int ot = 0; ot < 4; ++ot)
        wf[ot] = load_w_frag(wsrc + (ot * 16 + l15) * 128 + kk * 32 + quad * 8, ws);
      #pragma unroll
      for (int nt = 0; nt < 2; ++nt)
        xf[nt] = *(const short8*)(xl + (nt * 16 + l15) * 136 + kk * 32 + quad * 8);
      #pragma unroll
      for (int i = 0; i < 2; ++i)
        #pragma unroll
        for (int j = 0; j < 4; ++j)
          acc[i][j] = __builtin_amdgcn_mfma_f32_16x16x32_bf16(xf[i], wf[j], acc[i][j], 0, 0, 0);
    }

    u16* dst = (conv ? K : Q) + (size_t)b * 4096 * 64;
    const float* bias = conv ? pb : tb;
    const float bscale = conv ? 1.f : LOG2E;
    #pragma unroll
    for (int ot = 0; ot < 4; ++ot) {
      const float bv = bias[ot * 16 + l15] * bscale;
      #pragma unroll
      for (int nt = 0; nt < 2; ++nt)
        #pragma unroll
        for (int r = 0; r < 4; ++r) {
          const int n = n0 + nt * 16 + quad * 4 + r;
          dst[(size_t)n * 64 + ot * 16 + l15] = f2b(acc[nt][ot][r] + bv);
        }
    }
  } else {
    const int oh = wave - 2;            // g(x0)->Vt
    const short* xl = &xt[0][0][0];

    f32x4 acc[2][2];
    #pragma unroll
    for (int i = 0; i < 2; ++i)
      #pragma unroll
      for (int j = 0; j < 2; ++j) acc[i][j] = (f32x4){0.f, 0.f, 0.f, 0.f};

    #pragma unroll
    for (int kk = 0; kk < 4; ++kk) {
      short8 wf[2], xf[2];
      #pragma unroll
      for (int ot = 0; ot < 2; ++ot)
        wf[ot] = load_w_frag(gw + ((oh * 2 + ot) * 16 + l15) * 128 + kk * 32 + quad * 8, 1.f);
      #pragma unroll
      for (int nt = 0; nt < 2; ++nt)
        xf[nt] = *(const short8*)(xl + (nt * 16 + l15) * 136 + kk * 32 + quad * 8);
      #pragma unroll
      for (int i = 0; i < 2; ++i)
        #pragma unroll
        for (int j = 0; j < 2; ++j)
          acc[i][j] = __builtin_amdgcn_mfma_f32_16x16x32_bf16(wf[i], xf[j], acc[i][j], 0, 0, 0);
    }

    u16* dst = Vt + (size_t)b * 64 * 4096;
    #pragma unroll
    for (int ot = 0; ot < 2; ++ot)
      #pragma unroll
      for (int r = 0; r < 4; ++r) {
        const int o = (oh * 2 + ot) * 16 + quad * 4 + r;
        const float bv = gb[o];
        #pragma unroll
        for (int nc = 0; nc < 2; ++nc)
          dst[(size_t)o * 4096 + n0 + nc * 16 + l15] = f2b(acc[ot][nc][r] + bv);
      }
  }
}

// grid (16 qt, 4 b, 16 ks) = 1024 blocks (4/CU). Verified core; exp via raw v_exp_f32.
__global__ __launch_bounds__(256) void attn_kernel(
    const u16* __restrict__ Q, const u16* __restrict__ K,
    const u16* __restrict__ Vt, u16* __restrict__ Opart,
    float* __restrict__ Lp)
{
  const int qt = blockIdx.x, b = blockIdx.y, ks = blockIdx.z;
  const int tid  = threadIdx.x;
  const int wave = tid >> 6;
  const int lane = tid & 63;
  const int quad = lane >> 4;
  const int l15  = lane & 15;

  __shared__ __align__(16) short P_lds[4][64][72];
  short* pl = &P_lds[wave][0][0];

  const int q0 = qt * 256 + wave * 64;
  const u16* Qb = Q  + (size_t)b * 4096 * 64;
  const u16* Kb = K  + (size_t)b * 4096 * 64;
  const u16* Vb = Vt + (size_t)b * 64 * 4096;

  short8 qf[4][2];
  #pragma unroll
  for (int nt = 0; nt < 4; ++nt) {
    const u16* qp = Qb + (size_t)(q0 + nt * 16 + l15) * 64 + quad * 8;
    qf[nt][0] = *(const short8*)qp;
    qf[nt][1] = *(const short8*)(qp + 32);
  }

  f32x4 oacc[4][4];
  #pragma unroll
  for (int i = 0; i < 4; ++i)
    #pragma unroll
    for (int j = 0; j < 4; ++j)
      oacc[i][j] = (f32x4){0.f, 0.f, 0.f, 0.f};
  float lsum[4] = {0.f, 0.f, 0.f, 0.f};

  const int kbase = ks * (4096 / KSPLIT);
  const int NKT   = 4096 / KSPLIT / 64;   // 4

  short8 kf[4][2];
  #pragma unroll
  for (int mt = 0; mt < 4; ++mt) {
    const u16* kp = Kb + (size_t)(kbase + mt * 16 + l15) * 64 + quad * 8;
    kf[mt][0] = *(const short8*)kp;
    kf[mt][1] = *(const short8*)(kp + 32);
  }

  for (int kt = 0; kt < NKT; ++kt) {
    const int k0 = kbase + kt * 64;

    short8 vf[4][2];
    #pragma unroll
    for (int nd = 0; nd < 4; ++nd) {
      const u16* vp = Vb + (size_t)(nd * 16 + l15) * 4096 + k0 + quad * 8;
      vf[nd][0] = *(const short8*)vp;
      vf[nd][1] = *(const short8*)(vp + 32);
    }

    #pragma unroll
    for (int mt = 0; mt < 4; ++mt) {
      #pragma unroll
      for (int nt = 0; nt < 4; ++nt) {
        f32x4 s = {0.f, 0.f, 0.f, 0.f};
        s = __builtin_amdgcn_mfma_f32_16x16x32_bf16(kf[mt][0], qf[nt][0], s, 0, 0, 0);
        s = __builtin_amdgcn_mfma_f32_16x16x32_bf16(kf[mt][1], qf[nt][1], s, 0, 0, 0);
        // raw v_exp_f32 — logits bounded so fast path safe (verified R13, absmax unchanged)
        float p0 = __builtin_amdgcn_exp2f(s[0]);
        float p1 = __builtin_amdgcn_exp2f(s[1]);
        float p2 = __builtin_amdgcn_exp2f(s[2]);
        float p3 = __builtin_amdgcn_exp2f(s[3]);
        lsum[nt] += (p0 + p1) + (p2 + p3);
        u32 u0 = __float_as_uint(p0) + 0x8000u;
        u32 u1 = __float_as_uint(p1) + 0x8000u;
        u32 u2 = __float_as_uint(p2) + 0x8000u;
        u32 u3 = __float_as_uint(p3) + 0x8000u;
        union { uint2 u; short4v s4; } pk;
        pk.u.x = __builtin_amdgcn_perm(u1, u0, 0x07060302u);
        pk.u.y = __builtin_amdgcn_perm(u3, u2, 0x07060302u);
        *(short4v*)(pl + (nt * 16 + l15) * 72 + mt * 16 + quad * 4) = pk.s4;
      }
    }

    if (kt < NKT - 1) {
      #pragma unroll
      for (int mt = 0; mt < 4; ++mt) {
        const u16* kp = Kb + (size_t)(k0 + 64 + mt * 16 + l15) * 64 + quad * 8;
        kf[mt][0] = *(const short8*)kp;
        kf[mt][1] = *(const short8*)(kp + 32);
      }
    }

    asm volatile("" ::: "memory");   // S-phase LDS writes before PV reads

    #pragma unroll
    for (int mq = 0; mq < 4; ++mq) {
      const short* pr = pl + (mq * 16 + l15) * 72 + quad * 8;
      short8 pa0 = *(const short8*)pr;
      short8 pa1 = *(const short8*)(pr + 32);
      #pragma unroll
      for (int nd = 0; nd < 4; ++nd) {
        oacc[mq][nd] = __builtin_amdgcn_mfma_f32_16x16x32_bf16(pa0, vf[nd][0], oacc[mq][nd], 0, 0, 0);
        oacc[mq][nd] = __builtin_amdgcn_mfma_f32_16x16x32_bf16(pa1, vf[nd][1], oacc[mq][nd], 0, 0, 0);
      }
    }

    asm volatile("" ::: "memory");   // PV reads before next kt overwrites P
  }

  #pragma unroll
  for (int nt = 0; nt < 4; ++nt) {
    float v = lsum[nt];
    v += __shfl_xor(v, 16, 64);
    v += __shfl_xor(v, 32, 64);
    lsum[nt] = v;
  }
  float* LpB = Lp + ((size_t)ks * 4 + b) * 4096;
  if (quad == 0) {
    #pragma unroll
    for (int nt = 0; nt < 4; ++nt)
      LpB[q0 + nt * 16 + l15] = lsum[nt];
  }

  u16* Ob = Opart + ((size_t)ks * 4 + b) * 4096 * 64;
  #pragma unroll
  for (int mq = 0; mq < 4; ++mq)
    #pragma unroll
    for (int nd = 0; nd < 4; ++nd)
      #pragma unroll
      for (int r = 0; r < 4; ++r) {
        const int q = q0 + mq * 16 + quad * 4 + r;
        Ob[(size_t)q * 64 + nd * 16 + l15] = f2b(oacc[mq][nd][r]);
      }
}

// grid (128 n-tiles of 32, 4 batches), block 256 = 4 waves. LDS 4.6 KB.
__global__ __launch_bounds__(256) void out_kernel(
    const u16* __restrict__ Opart, const float* __restrict__ Lp,
    const float* __restrict__ Wf, const float* __restrict__ Wbf,
    const float* __restrict__ x0, float* __restrict__ out)
{
  const int n0 = blockIdx.x * 32;
  const int b  = blockIdx.y;
  const int t  = threadIdx.x;

  __shared__ __align__(16) short Ys[32][72];   // [n][ci], +8 pad

  {
    const int nl = t >> 3;          // 0..31
    const int q8 = t & 7;           // 8-ch chunk (one uint4)
    const int ng = n0 + nl;

    float l = 0.f;
    #pragma unroll
    for (int ks = 0; ks < KSPLIT; ++ks)
      l += Lp[((size_t)ks * 4 + b) * 4096 + ng];

    float a[8];
    #pragma unroll
    for (int j = 0; j < 8; ++j) a[j] = 0.f;
    #pragma unroll
    for (int ks = 0; ks < KSPLIT; ++ks) {
      const uint4 r = *(const uint4*)(Opart + (((size_t)ks * 4 + b) * 4096 + ng) * 64 + q8 * 8);
      u32 wds[4] = {r.x, r.y, r.z, r.w};
      #pragma unroll
      for (int j = 0; j < 4; ++j) {
        a[2 * j]     += __uint_as_float(wds[j] << 16);
        a[2 * j + 1] += __uint_as_float(wds[j] & 0xffff0000u);
      }
    }
    const float rinv = 1.f / l;
    union { u32 w[4]; short8 s8; } pk;
    #pragma unroll
    for (int j = 0; j < 4; ++j)
      pk.w[j] = (u32)f2b(a[2 * j] * rinv) | ((u32)f2b(a[2 * j + 1] * rinv) << 16);
    *(short8*)&Ys[nl][q8 * 8] = pk.s8;
  }
  asm volatile("" ::: "memory");
  __syncthreads();

  const int wave = t >> 6;
  const int lane = t & 63;
  const int quad = lane >> 4, l15 = lane & 15;

  f32x4 acc[2][2];   // [o-tile within wave][n-tile]
  #pragma unroll
  for (int i = 0; i < 2; ++i)
    #pragma unroll
    for (int j = 0; j < 2; ++j) acc[i][j] = (f32x4){0.f, 0.f, 0.f, 0.f};

  #pragma unroll
  for (int kk = 0; kk < 2; ++kk) {
    short8 wf[2], yf[2];
    #pragma unroll
    for (int ot = 0; ot < 2; ++ot)
      wf[ot] = load_w_frag(Wf + ((wave * 2 + ot) * 16 + l15) * 64 + kk * 32 + quad * 8, 1.f);
    #pragma unroll
    for (int nt = 0; nt < 2; ++nt)
      yf[nt] = *(const short8*)&Ys[nt * 16 + l15][kk * 32 + quad * 8];
    #pragma unroll
    for (int i = 0; i < 2; ++i)
      #pragma unroll
      for (int j = 0; j < 2; ++j)
        acc[i][j] = __builtin_amdgcn_mfma_f32_16x16x32_bf16(wf[i], yf[j], acc[i][j], 0, 0, 0);
  }

  #pragma unroll
  for (int ot = 0; ot < 2; ++ot)
    #pragma unroll
    for (int r = 0; r < 4; ++r) {
      const int o = (wave * 2 + ot) * 16 + quad * 4 + r;
      const float bv = Wbf[o];
      #pragma unroll
      for (int nt = 0; nt < 2; ++nt) {
        const size_t idx = ((size_t)(b * 128 + o)) * 4096 + n0 + nt * 16 + l15;
        out[idx] = acc[ot][nt][r] + bv + x0[idx];
      }
    }
}

extern "C" void kernel_launch(void* const* d_in, const int* in_sizes, int n_in,
                              void* d_out, int out_size, void* d_ws, size_t ws_size,
                              hipStream_t stream) {
  const float* x0 = (const float*)d_in[0];
  const float* x1 = (const float*)d_in[1];
  const float* gw = (const float*)d_in[2];
  const float* gb = (const float*)d_in[3];
  const float* tw = (const float*)d_in[4];
  const float* tb = (const float*)d_in[5];
  const float* pw = (const float*)d_in[6];
  const float* pb = (const float*)d_in[7];
  const float* Ww = (const float*)d_in[8];
  const float* Wb = (const float*)d_in[9];
  float* out = (float*)d_out;

  char* ws = (char*)d_ws;
  u16*   Qw    = (u16*)(ws + 0);
  u16*   Kw    = (u16*)(ws + (2u << 20));
  u16*   Vtw   = (u16*)(ws + (4u << 20));
  u16*   Opart = (u16*)(ws + (6u << 20));
  float* Lp    = (float*)(ws + (38u << 20));   // 39 MB total

  qkv_kernel<<<dim3(128, 4), dim3(256), 0, stream>>>(
      x0, x1, tw, tb, pw, pb, gw, gb, Qw, Kw, Vtw);

  attn_kernel<<<dim3(16, 4, KSPLIT), dim3(256), 0, stream>>>(Qw, Kw, Vtw, Opart, Lp);

  out_kernel<<<dim3(128, 4), dim3(256), 0, stream>>>(
      Opart, Lp, Ww, Wb, x0, out);
}